// Round 10
// baseline (228.670 us; speedup 1.0000x reference)
//
#include <hip/hip_runtime.h>
#include <stdint.h>

#define N_ROWS 4096
#define Z_DIM  2048
#define TOT    8192           // 2N rows of reps
#define TILE   128
#define RBYTES (Z_DIM / 2)    // 1024 B per fp4 row
#define BKE    128            // K elements per MFMA step
#define KBYT   (BKE / 2)      // 64 B per row per step
#define NITER  (Z_DIM / BKE)  // 16
#define NT     (TOT / TILE)   // 64 tile-columns
#define NBLK   (NT * (NT + 1) / 2)   // 2080 triangular blocks (2080%8==0)
#define INV_T  2.0f           // 1/temperature
#define SCL4   64.0f          // fp4 pre-scale; logits = acc * INV_T / SCL4^2

typedef __attribute__((ext_vector_type(4))) int   intx4;
typedef __attribute__((ext_vector_type(8))) int   intx8;
typedef __attribute__((ext_vector_type(4))) float floatx4;

// branchless f32 -> fp4 e2m1 code (round to nearest level)
// levels: 0,0.5,1,1.5,2,3,4,6 ; thresholds at midpoints
__device__ __forceinline__ unsigned int f2fp4(float v) {
    float a = fabsf(v);
    unsigned int c = (a >= 0.25f) + (a >= 0.75f) + (a >= 1.25f) + (a >= 1.75f)
                   + (a >= 2.5f)  + (a >= 3.5f)  + (a >= 5.0f);
    return c | (v < 0.f ? 8u : 0u);
}

// ---------------- kernel 1: row-normalize to fp4(e2m1, x64), pos, zero rowsum
__global__ __launch_bounds__(256) void normalize_kernel(
    const float* __restrict__ z1, const float* __restrict__ z2,
    unsigned char* __restrict__ reps, float* __restrict__ pos,
    float* __restrict__ rowsum)
{
    const int row  = blockIdx.x;          // 0..4095
    const int tid  = threadIdx.x;         // 0..255, 8 floats each
    const int lane = tid & 63, wave = tid >> 6;

    if (row < TOT / 256) rowsum[row * 256 + tid] = 0.f;   // fold in memset

    const float4* p1 = (const float4*)(z1 + (size_t)row * Z_DIM);
    const float4* p2 = (const float4*)(z2 + (size_t)row * Z_DIM);
    float4 x0 = p1[tid * 2], x1 = p1[tid * 2 + 1];
    float4 y0 = p2[tid * 2], y1 = p2[tid * 2 + 1];

    float s1 = x0.x*x0.x + x0.y*x0.y + x0.z*x0.z + x0.w*x0.w
             + x1.x*x1.x + x1.y*x1.y + x1.z*x1.z + x1.w*x1.w;
    float s2 = y0.x*y0.x + y0.y*y0.y + y0.z*y0.z + y0.w*y0.w
             + y1.x*y1.x + y1.y*y1.y + y1.z*y1.z + y1.w*y1.w;
    float dd = x0.x*y0.x + x0.y*y0.y + x0.z*y0.z + x0.w*y0.w
             + x1.x*y1.x + x1.y*y1.y + x1.z*y1.z + x1.w*y1.w;

    #pragma unroll
    for (int m = 1; m < 64; m <<= 1) {
        s1 += __shfl_xor(s1, m);
        s2 += __shfl_xor(s2, m);
        dd += __shfl_xor(dd, m);
    }
    __shared__ float red[3][4];
    if (lane == 0) { red[0][wave] = s1; red[1][wave] = s2; red[2][wave] = dd; }
    __syncthreads();
    s1 = red[0][0] + red[0][1] + red[0][2] + red[0][3];
    s2 = red[1][0] + red[1][1] + red[1][2] + red[1][3];
    dd = red[2][0] + red[2][1] + red[2][2] + red[2][3];

    const float inv1 = rsqrtf(s1), inv2 = rsqrtf(s2);
    if (tid == 0) {
        float p = dd * inv1 * inv2 * INV_T;   // pos in full fp32 precision
        pos[row] = p;
        pos[row + N_ROWS] = p;
    }

    // fp4 encode of (normalized * 64): sigma ~1.4, range to ~6 (rare clip).
    // elem k -> byte k/2, LOW nibble = even k.
    const float a = inv1 * SCL4, b = inv2 * SCL4;
    unsigned int pa =  f2fp4(x0.x * a)        | (f2fp4(x0.y * a) << 4)
                    | (f2fp4(x0.z * a) << 8)  | (f2fp4(x0.w * a) << 12)
                    | (f2fp4(x1.x * a) << 16) | (f2fp4(x1.y * a) << 20)
                    | (f2fp4(x1.z * a) << 24) | (f2fp4(x1.w * a) << 28);
    unsigned int pb =  f2fp4(y0.x * b)        | (f2fp4(y0.y * b) << 4)
                    | (f2fp4(y0.z * b) << 8)  | (f2fp4(y0.w * b) << 12)
                    | (f2fp4(y1.x * b) << 16) | (f2fp4(y1.y * b) << 20)
                    | (f2fp4(y1.z * b) << 24) | (f2fp4(y1.w * b) << 28);
    *(unsigned int*)(reps + (size_t)row * RBYTES + tid * 4) = pa;
    *(unsigned int*)(reps + (size_t)(N_ROWS + row) * RBYTES + tid * 4) = pb;
}

// ---------------- kernel 2: triangular S = reps@reps^T, MX-fp4 K=128 --------
// BARRIER-FREE: fragments load straight from global memory to registers.
// Rationale (rounds 0-9): the LDS-staged 2-phase loop is stall-bound --
// MfmaUtil pinned at 21-24% with conflicts=0, counted-vmcnt and occupancy
// sweeps exhausted. reps is 8 MiB (L2/LLC-resident) and a wave's fragment
// load coalesces to 16 rows x 64 B = 1 KiB/instr -- the SAME L2-line count
// as the staging path. So LDS staging buys no traffic reduction and costs
// the DMA + 8 ds_reads + vmcnt drain + barrier on every K-step (the ~45%
// no-issue stall). Drop it all: no LDS, no __syncthreads, no vmcnt asm.
// One-step register prefetch; unroll 2 so the compiler renames buffers
// (no rotate copies). setprio kept: independent drifting waves are exactly
// the regime where MFMA-priority pays. XCD-chunked block swizzle kept for
// A/B panel L2 locality.
__global__ __launch_bounds__(256) void simclr_gemm(
    const unsigned char* __restrict__ reps, float* __restrict__ rowsum)
{
    // XCD-aware chunked swizzle, then decode to lower-triangle (r >= c)
    const int bid = blockIdx.x;
    const int t = (bid & 7) * (NBLK / 8) + (bid >> 3);
    int r = (int)((sqrtf(8.0f * (float)t + 1.0f) - 1.0f) * 0.5f);
    while ((r + 1) * (r + 2) / 2 <= t) ++r;
    while (r * (r + 1) / 2 > t) --r;
    const int bi = t - r * (r + 1) / 2;   // <= bj
    const int bj = r;
    const bool diag = (bi == bj);

    const int tid  = threadIdx.x;
    const int lane = tid & 63, wave = tid >> 6;
    const int wr = wave >> 1, wc = wave & 1;       // 2x2 waves over 128x128
    const int quad = lane >> 4, l16 = lane & 15;
    const int row0 = bi * TILE, col0 = bj * TILE;

    floatx4 acc[4][4];
    #pragma unroll
    for (int i = 0; i < 4; ++i)
        #pragma unroll
        for (int j = 0; j < 4; ++j)
            acc[i][j] = floatx4{0.f, 0.f, 0.f, 0.f};

    // per-lane fragment base addresses; step i adds i*64 B (immediate-foldable)
    // A frag fi: row row0 + wr*64 + fi*16 + l16, k-chunk quad (16 B).
    const unsigned char* pA[4];
    const unsigned char* pB[4];
    #pragma unroll
    for (int fi = 0; fi < 4; ++fi) {
        pA[fi] = reps + (size_t)(row0 + wr * 64 + fi * 16 + l16) * RBYTES
                      + quad * 16;
        pB[fi] = reps + (size_t)(col0 + wc * 64 + fi * 16 + l16) * RBYTES
                      + quad * 16;
    }

    // prologue: step-0 fragments
    intx4 ca[4], cb[4];
    #pragma unroll
    for (int fi = 0; fi < 4; ++fi) {
        ca[fi] = *(const intx4*)pA[fi];
        cb[fi] = *(const intx4*)pB[fi];
    }

    #pragma unroll 2
    for (int i = 0; i < NITER; ++i) {
        // prefetch step i+1 into fresh registers (loads issue before the
        // MFMA cluster; their latency hides under it + other waves)
        intx4 na[4], nb[4];
        if (i + 1 < NITER) {
            const int ko = (i + 1) * KBYT;
            #pragma unroll
            for (int fi = 0; fi < 4; ++fi) {
                na[fi] = *(const intx4*)(pA[fi] + ko);
                nb[fi] = *(const intx4*)(pB[fi] + ko);
            }
        }

        // FMT=fp4 reads only v[0:3] of the 8-reg operand; upper half zero.
        intx8 af[4], bf[4];
        #pragma unroll
        for (int fi = 0; fi < 4; ++fi) {
            af[fi] = intx8{ca[fi][0], ca[fi][1], ca[fi][2], ca[fi][3], 0,0,0,0};
            bf[fi] = intx8{cb[fi][0], cb[fi][1], cb[fi][2], cb[fi][3], 0,0,0,0};
        }
        __builtin_amdgcn_s_setprio(1);
        #pragma unroll
        for (int fi = 0; fi < 4; ++fi)
            #pragma unroll
            for (int j = 0; j < 4; ++j)
                acc[fi][j] = __builtin_amdgcn_mfma_scale_f32_16x16x128_f8f6f4(
                    af[fi], bf[j], acc[fi][j],
                    4, 4,                      // cbsz=fp4(A), blgp=fp4(B)
                    0, 0x7F7F7F7Fu,            // scale_a = 1.0 (E8M0)
                    0, 0x7F7F7F7Fu);           // scale_b = 1.0
        __builtin_amdgcn_s_setprio(0);

        if (i + 1 < NITER) {
            #pragma unroll
            for (int fi = 0; fi < 4; ++fi) { ca[fi] = na[fi]; cb[fi] = nb[fi]; }
        }
    }

    // Epilogue: C/D layout col = lane&15, row = quad*4 + reg.
    // logit = acc * INV_T / SCL4^2; |logit| <= 2 so plain exp-sum is safe.
    const float descale = INV_T / (SCL4 * SCL4);   // 1/2048
    float scol[4] = {0.f, 0.f, 0.f, 0.f};
    #pragma unroll
    for (int fi = 0; fi < 4; ++fi) {
        const int rbase = row0 + wr * 64 + fi * 16 + quad * 4;
        float srow[4] = {0.f, 0.f, 0.f, 0.f};
        #pragma unroll
        for (int j = 0; j < 4; ++j) {
            const int c = col0 + wc * 64 + j * 16 + l16;
            #pragma unroll
            for (int rr = 0; rr < 4; ++rr) {
                float e = __expf(acc[fi][j][rr] * descale);
                if (diag && (rbase + rr == c)) e = 0.f;  // exclude self-sim
                srow[rr] += e;
                scol[j]  += e;
            }
        }
        #pragma unroll
        for (int rr = 0; rr < 4; ++rr) {
            #pragma unroll
            for (int m = 1; m < 16; m <<= 1) srow[rr] += __shfl_xor(srow[rr], m);
        }
        if (l16 == 0) {
            #pragma unroll
            for (int rr = 0; rr < 4; ++rr)
                atomicAdd(&rowsum[rbase + rr], srow[rr]);
        }
    }
    if (!diag) {   // symmetry credit: column sums -> mirrored rows
        #pragma unroll
        for (int j = 0; j < 4; ++j) {
            scol[j] += __shfl_xor(scol[j], 16);
            scol[j] += __shfl_xor(scol[j], 32);
        }
        if (quad == 0) {
            #pragma unroll
            for (int j = 0; j < 4; ++j)
                atomicAdd(&rowsum[col0 + wc * 64 + j * 16 + l16], scol[j]);
        }
    }
}

// ---------------- kernel 3: mean(log(rowsum) - pos) ----------------
__global__ __launch_bounds__(1024) void finalize_kernel(
    const float* __restrict__ rowsum, const float* __restrict__ pos,
    float* __restrict__ out)
{
    const int tid = threadIdx.x;
    const int lane = tid & 63, wave = tid >> 6;
    float s = 0.f;
    for (int r = tid; r < TOT; r += 1024) s += logf(rowsum[r]) - pos[r];
    #pragma unroll
    for (int m = 1; m < 64; m <<= 1) s += __shfl_xor(s, m);
    __shared__ float red[16];
    if (lane == 0) red[wave] = s;
    __syncthreads();
    if (tid == 0) {
        float t = 0.f;
        #pragma unroll
        for (int w = 0; w < 16; ++w) t += red[w];
        out[0] = t * (1.0f / TOT);
    }
}

extern "C" void kernel_launch(void* const* d_in, const int* in_sizes, int n_in,
                              void* d_out, int out_size, void* d_ws, size_t ws_size,
                              hipStream_t stream)
{
    const float* z1 = (const float*)d_in[0];
    const float* z2 = (const float*)d_in[1];
    float* out = (float*)d_out;

    char* w = (char*)d_ws;
    unsigned char* reps = (unsigned char*)w;                 // 8 MiB fp4 [8192][1024B]
    float* pos    = (float*)(w + (size_t)TOT * RBYTES);      // 32 KiB
    float* rowsum = pos + TOT;                               // 32 KiB

    normalize_kernel<<<N_ROWS, 256, 0, stream>>>(z1, z2, reps, pos, rowsum);
    simclr_gemm<<<NBLK, 256, 0, stream>>>(reps, rowsum);
    finalize_kernel<<<1, 1024, 0, stream>>>(rowsum, pos, out);
}

// Round 11
// 147.371 us; speedup vs baseline: 1.5517x; 1.5517x over previous
//
#include <hip/hip_runtime.h>
#include <stdint.h>

#define N_ROWS 4096
#define Z_DIM  2048
#define TOT    8192           // 2N rows of reps
#define TILE   128
#define RBYTES (Z_DIM / 2)    // 1024 B per fp4 row
#define BKE    128            // K elements per staging round
#define KBYT   (BKE / 2)      // 64 B per row per staging round
#define NITER  (Z_DIM / BKE)  // 16
#define NT     (TOT / TILE)   // 64 tile-columns
#define NBLK   (NT * (NT + 1) / 2)   // 2080 triangular blocks (2080%8==0)
#define INV_T  2.0f           // 1/temperature
#define SCL4   64.0f          // fp4 pre-scale; logits = acc * INV_T / SCL4^2

typedef __attribute__((ext_vector_type(4))) int   intx4;
typedef __attribute__((ext_vector_type(8))) int   intx8;
typedef __attribute__((ext_vector_type(4))) float floatx4;

#define GLOAD16(g, l)                                                   \
    __builtin_amdgcn_global_load_lds(                                   \
        (const __attribute__((address_space(1))) unsigned int*)(g),     \
        (__attribute__((address_space(3))) unsigned int*)(l), 16, 0, 0)

// branchless f32 -> fp4 e2m1 code (round to nearest level)
// levels: 0,0.5,1,1.5,2,3,4,6 ; thresholds at midpoints
__device__ __forceinline__ unsigned int f2fp4(float v) {
    float a = fabsf(v);
    unsigned int c = (a >= 0.25f) + (a >= 0.75f) + (a >= 1.25f) + (a >= 1.75f)
                   + (a >= 2.5f)  + (a >= 3.5f)  + (a >= 5.0f);
    return c | (v < 0.f ? 8u : 0u);
}

// ---------------- kernel 1: row-normalize to fp4(e2m1, x64), pos, zero rowsum
__global__ __launch_bounds__(256) void normalize_kernel(
    const float* __restrict__ z1, const float* __restrict__ z2,
    unsigned char* __restrict__ reps, float* __restrict__ pos,
    float* __restrict__ rowsum)
{
    const int row  = blockIdx.x;          // 0..4095
    const int tid  = threadIdx.x;         // 0..255, 8 floats each
    const int lane = tid & 63, wave = tid >> 6;

    if (row < TOT / 256) rowsum[row * 256 + tid] = 0.f;   // fold in memset

    const float4* p1 = (const float4*)(z1 + (size_t)row * Z_DIM);
    const float4* p2 = (const float4*)(z2 + (size_t)row * Z_DIM);
    float4 x0 = p1[tid * 2], x1 = p1[tid * 2 + 1];
    float4 y0 = p2[tid * 2], y1 = p2[tid * 2 + 1];

    float s1 = x0.x*x0.x + x0.y*x0.y + x0.z*x0.z + x0.w*x0.w
             + x1.x*x1.x + x1.y*x1.y + x1.z*x1.z + x1.w*x1.w;
    float s2 = y0.x*y0.x + y0.y*y0.y + y0.z*y0.z + y0.w*y0.w
             + y1.x*y1.x + y1.y*y1.y + y1.z*y1.z + y1.w*y1.w;
    float dd = x0.x*y0.x + x0.y*y0.y + x0.z*y0.z + x0.w*y0.w
             + x1.x*y1.x + x1.y*y1.y + x1.z*y1.z + x1.w*y1.w;

    #pragma unroll
    for (int m = 1; m < 64; m <<= 1) {
        s1 += __shfl_xor(s1, m);
        s2 += __shfl_xor(s2, m);
        dd += __shfl_xor(dd, m);
    }
    __shared__ float red[3][4];
    if (lane == 0) { red[0][wave] = s1; red[1][wave] = s2; red[2][wave] = dd; }
    __syncthreads();
    s1 = red[0][0] + red[0][1] + red[0][2] + red[0][3];
    s2 = red[1][0] + red[1][1] + red[1][2] + red[1][3];
    dd = red[2][0] + red[2][1] + red[2][2] + red[2][3];

    const float inv1 = rsqrtf(s1), inv2 = rsqrtf(s2);
    if (tid == 0) {
        float p = dd * inv1 * inv2 * INV_T;   // pos in full fp32 precision
        pos[row] = p;
        pos[row + N_ROWS] = p;
    }

    // fp4 encode of (normalized * 64): sigma ~1.4, range to ~6 (rare clip).
    // elem k -> byte k/2, LOW nibble = even k.
    const float a = inv1 * SCL4, b = inv2 * SCL4;
    unsigned int pa =  f2fp4(x0.x * a)        | (f2fp4(x0.y * a) << 4)
                    | (f2fp4(x0.z * a) << 8)  | (f2fp4(x0.w * a) << 12)
                    | (f2fp4(x1.x * a) << 16) | (f2fp4(x1.y * a) << 20)
                    | (f2fp4(x1.z * a) << 24) | (f2fp4(x1.w * a) << 28);
    unsigned int pb =  f2fp4(y0.x * b)        | (f2fp4(y0.y * b) << 4)
                    | (f2fp4(y0.z * b) << 8)  | (f2fp4(y0.w * b) << 12)
                    | (f2fp4(y1.x * b) << 16) | (f2fp4(y1.y * b) << 20)
                    | (f2fp4(y1.z * b) << 24) | (f2fp4(y1.w * b) << 28);
    *(unsigned int*)(reps + (size_t)row * RBYTES + tid * 4) = pa;
    *(unsigned int*)(reps + (size_t)(N_ROWS + row) * RBYTES + tid * 4) = pb;
}

// ---------------- kernel 2: triangular S = reps@reps^T, MX-fp4 K=128 --------
// CHAMPION (round-9 file, 147.9 us e2e measured): 128x128 tile, 2x2 waves,
// conflict-free (row>>1)&3 swizzle, triple-buffered A+B (48 KiB, 3
// blocks/CU), counted `s_waitcnt vmcnt(4)` + raw barrier per K-step,
// XCD-chunked block swizzle, ds_read hoist above prefetch, separate
// finalize. Session-falsified alternatives (do NOT revisit):
//  - 8-phase deep pipeline @256-tile: tail+occupancy loss (r1/r2)
//  - 4 blocks/CU reg diet: serialized inner loop (r5)
//  - fused finalize: threadfence=L2-writeback scan, counter serialization
//    (r6-r8, -35 us on gemm)
//  - global->reg operand fetch, no LDS: L1 request-rate bound, 2.2x (r10)
__global__ __launch_bounds__(256) void simclr_gemm(
    const unsigned char* __restrict__ reps, float* __restrict__ rowsum)
{
    __shared__ __align__(16) unsigned char L[3][2][TILE * KBYT];   // 48 KiB

    // XCD-aware chunked swizzle, then decode to lower-triangle (r >= c)
    const int bid = blockIdx.x;
    const int t = (bid & 7) * (NBLK / 8) + (bid >> 3);
    int r = (int)((sqrtf(8.0f * (float)t + 1.0f) - 1.0f) * 0.5f);
    while ((r + 1) * (r + 2) / 2 <= t) ++r;
    while (r * (r + 1) / 2 > t) --r;
    const int bi = t - r * (r + 1) / 2;   // <= bj
    const int bj = r;
    const bool diag = (bi == bj);

    const int tid  = threadIdx.x;
    const int lane = tid & 63, wave = tid >> 6;
    const int wr = wave >> 1, wc = wave & 1;       // 2x2 waves over 128x128
    const int quad = lane >> 4, l16 = lane & 15;
    const int sw   = (l16 >> 1) & 3;               // read-side XOR swizzle key
    const int row0 = bi * TILE, col0 = bj * TILE;

    floatx4 acc[4][4];
    #pragma unroll
    for (int i = 0; i < 4; ++i)
        #pragma unroll
        for (int j = 0; j < 4; ++j)
            acc[i][j] = floatx4{0.f, 0.f, 0.f, 0.f};

    // staging: 512 chunks of 16B per operand (128 rows x 4 chunks); thread
    // handles chunks tid and tid+256. LDS slot c holds global chunk
    // ((c&3) ^ (((c>>2)>>1)&3)) of row c>>2.
    const int c0 = tid, c1 = tid + 256;
    const int r0s = c0 >> 2, k0s = (c0 & 3) ^ ((r0s >> 1) & 3);
    const int r1s = c1 >> 2, k1s = (c1 & 3) ^ ((r1s >> 1) & 3);
    const unsigned char* gA0 = reps + (size_t)(row0 + r0s) * RBYTES + k0s * 16;
    const unsigned char* gA1 = reps + (size_t)(row0 + r1s) * RBYTES + k1s * 16;
    const unsigned char* gB0 = reps + (size_t)(col0 + r0s) * RBYTES + k0s * 16;
    const unsigned char* gB1 = reps + (size_t)(col0 + r1s) * RBYTES + k1s * 16;
    const int o0 = c0 * 16, o1 = c1 * 16;

    // prologue: steps 0,1 -> buffers 0,1 (8 loads/thread in flight)
    GLOAD16(gA0, &L[0][0][o0]);
    GLOAD16(gA1, &L[0][0][o1]);
    GLOAD16(gB0, &L[0][1][o0]);
    GLOAD16(gB1, &L[0][1][o1]);
    GLOAD16(gA0 + KBYT, &L[1][0][o0]);
    GLOAD16(gA1 + KBYT, &L[1][0][o1]);
    GLOAD16(gB0 + KBYT, &L[1][1][o0]);
    GLOAD16(gB1 + KBYT, &L[1][1][o1]);

    int cur = 0;
    #pragma unroll 1
    for (int i = 0; i < NITER; ++i) {
        // complete step i's 4 loads (oldest); leave step i+1's 4 in flight
        if (i + 1 < NITER) asm volatile("s_waitcnt vmcnt(4)" ::: "memory");
        else               asm volatile("s_waitcnt vmcnt(0)" ::: "memory");
        __builtin_amdgcn_s_barrier();
        asm volatile("" ::: "memory");

        const unsigned char* Ab = &L[cur][0][0];
        const unsigned char* Bb = &L[cur][1][0];

        // fragment reads FIRST (latency overlaps the prefetch issue below).
        // 32 fp4 nibbles (elems k=quad*32..+32) = 16 B = 1 b128 per frag.
        intx4 av[4], bv[4];
        #pragma unroll
        for (int fi = 0; fi < 4; ++fi) {
            const int ar = (wr * 64 + fi * 16 + l16) * KBYT;
            const int br = (wc * 64 + fi * 16 + l16) * KBYT;
            av[fi] = *(const intx4*)&Ab[ar + ((quad ^ sw) << 4)];
            bv[fi] = *(const intx4*)&Bb[br + ((quad ^ sw) << 4)];
        }

        if (i + 2 < NITER) {              // prefetch step i+2 into buf (i-1)%3
            const size_t ko = (size_t)(i + 2) * KBYT;
            int pf = cur + 2; if (pf >= 3) pf -= 3;
            GLOAD16(gA0 + ko, &L[pf][0][o0]);
            GLOAD16(gA1 + ko, &L[pf][0][o1]);
            GLOAD16(gB0 + ko, &L[pf][1][o0]);
            GLOAD16(gB1 + ko, &L[pf][1][o1]);
        }

        // FMT=fp4 reads only v[0:3] of the 8-reg operand; upper half zero.
        intx8 af[4], bf[4];
        #pragma unroll
        for (int fi = 0; fi < 4; ++fi) {
            af[fi] = intx8{av[fi][0], av[fi][1], av[fi][2], av[fi][3], 0,0,0,0};
            bf[fi] = intx8{bv[fi][0], bv[fi][1], bv[fi][2], bv[fi][3], 0,0,0,0};
        }
        __builtin_amdgcn_s_setprio(1);
        #pragma unroll
        for (int fi = 0; fi < 4; ++fi)
            #pragma unroll
            for (int j = 0; j < 4; ++j)
                acc[fi][j] = __builtin_amdgcn_mfma_scale_f32_16x16x128_f8f6f4(
                    af[fi], bf[j], acc[fi][j],
                    4, 4,                      // cbsz=fp4(A), blgp=fp4(B)
                    0, 0x7F7F7F7Fu,            // scale_a = 1.0 (E8M0)
                    0, 0x7F7F7F7Fu);           // scale_b = 1.0
        __builtin_amdgcn_s_setprio(0);
        cur = (cur == 2) ? 0 : cur + 1;
    }

    // Epilogue: C/D layout col = lane&15, row = quad*4 + reg.
    // logit = acc * INV_T / SCL4^2; |logit| <= 2 so plain exp-sum is safe.
    const float descale = INV_T / (SCL4 * SCL4);   // 1/2048
    float scol[4] = {0.f, 0.f, 0.f, 0.f};
    #pragma unroll
    for (int fi = 0; fi < 4; ++fi) {
        const int rbase = row0 + wr * 64 + fi * 16 + quad * 4;
        float srow[4] = {0.f, 0.f, 0.f, 0.f};
        #pragma unroll
        for (int j = 0; j < 4; ++j) {
            const int c = col0 + wc * 64 + j * 16 + l16;
            #pragma unroll
            for (int rr = 0; rr < 4; ++rr) {
                float e = __expf(acc[fi][j][rr] * descale);
                if (diag && (rbase + rr == c)) e = 0.f;  // exclude self-sim
                srow[rr] += e;
                scol[j]  += e;
            }
        }
        #pragma unroll
        for (int rr = 0; rr < 4; ++rr) {
            #pragma unroll
            for (int m = 1; m < 16; m <<= 1) srow[rr] += __shfl_xor(srow[rr], m);
        }
        if (l16 == 0) {
            #pragma unroll
            for (int rr = 0; rr < 4; ++rr)
                atomicAdd(&rowsum[rbase + rr], srow[rr]);
        }
    }
    if (!diag) {   // symmetry credit: column sums -> mirrored rows
        #pragma unroll
        for (int j = 0; j < 4; ++j) {
            scol[j] += __shfl_xor(scol[j], 16);
            scol[j] += __shfl_xor(scol[j], 32);
        }
        if (quad == 0) {
            #pragma unroll
            for (int j = 0; j < 4; ++j)
                atomicAdd(&rowsum[col0 + wc * 64 + j * 16 + l16], scol[j]);
        }
    }
}

// ---------------- kernel 3: mean(log(rowsum) - pos) ----------------
__global__ __launch_bounds__(1024) void finalize_kernel(
    const float* __restrict__ rowsum, const float* __restrict__ pos,
    float* __restrict__ out)
{
    const int tid = threadIdx.x;
    const int lane = tid & 63, wave = tid >> 6;
    float s = 0.f;
    for (int r = tid; r < TOT; r += 1024) s += logf(rowsum[r]) - pos[r];
    #pragma unroll
    for (int m = 1; m < 64; m <<= 1) s += __shfl_xor(s, m);
    __shared__ float red[16];
    if (lane == 0) red[wave] = s;
    __syncthreads();
    if (tid == 0) {
        float t = 0.f;
        #pragma unroll
        for (int w = 0; w < 16; ++w) t += red[w];
        out[0] = t * (1.0f / TOT);
    }
}

extern "C" void kernel_launch(void* const* d_in, const int* in_sizes, int n_in,
                              void* d_out, int out_size, void* d_ws, size_t ws_size,
                              hipStream_t stream)
{
    const float* z1 = (const float*)d_in[0];
    const float* z2 = (const float*)d_in[1];
    float* out = (float*)d_out;

    char* w = (char*)d_ws;
    unsigned char* reps = (unsigned char*)w;                 // 8 MiB fp4 [8192][1024B]
    float* pos    = (float*)(w + (size_t)TOT * RBYTES);      // 32 KiB
    float* rowsum = pos + TOT;                               // 32 KiB

    normalize_kernel<<<N_ROWS, 256, 0, stream>>>(z1, z2, reps, pos, rowsum);
    simclr_gemm<<<NBLK, 256, 0, stream>>>(reps, rowsum);
    finalize_kernel<<<1, 1024, 0, stream>>>(rowsum, pos, out);
}